// Round 4
// baseline (159.372 us; speedup 1.0000x reference)
//
#include <hip/hip_runtime.h>
#include <math.h>

// NoisyTopkRouter: x[T,2048] @ {Wg,Wn}[8,2048]^T -> logits[T,8] each,
// noisy = noise * softplus(noisy_pre) + gate; top-2 -> softmax -> scatter.
// T = 32768, D = 2048, E = 8, k = 2.
//
// R4: R3 spilled (64 accs, VGPR=60 reported, 273 MB scratch writes).
// New structure: LDS-staged x (coalesced global loads, padded rows for
// conflict-free reads) + per-lane token accumulators (16 VGPRs) + W on the
// scalar path (wave-uniform kq segment -> s_load). Prefetch next chunk's
// global loads under current chunk's FMAs.

#define RD 2048
#define RE 8
#define TOKB 64               // tokens per block
#define CH 128                // d's per chunk
#define NCH (RD / CH)         // 16 chunks
#define KQ 4                  // K-split: one quarter per wave
#define SEG (CH / KQ)         // 32 floats per thread per chunk
#define LROW (CH + 4)         // padded LDS row (132 floats) -> bank-safe
#define REDW 20               // padded reduction row (floats)

__global__ __launch_bounds__(256) void noisy_topk_router_kernel(
    const float* __restrict__ x,
    const float* __restrict__ Wg,
    const float* __restrict__ bg,
    const float* __restrict__ Wn,
    const float* __restrict__ bn,
    const float* __restrict__ noise,
    float* __restrict__ out_router,
    float* __restrict__ out_experts)
{
    __shared__ float smem[TOKB * LROW];   // 33792 B; overlaid by reduction buf

    const int tid = threadIdx.x;
    const int token = tid & 63;           // lane -> token within tile
    const int kq = tid >> 6;              // wave -> K quarter
    const int tokBase = blockIdx.x * TOKB;

    // ---- staging maps (thread tid stages 8 float4s per chunk) ----
    // flat f4 index i = s*256 + tid; token_s = s*8 + (tid>>5); col = (tid&31)*4
    const float* gbase = x + (size_t)(tokBase + (tid >> 5)) * RD + (tid & 31) * 4;
    const int lbase = (tid >> 5) * LROW + (tid & 31) * 4;

    float accg[RE], accn[RE];
#pragma unroll
    for (int e = 0; e < RE; ++e) { accg[e] = 0.f; accn[e] = 0.f; }

    // preload chunk 0
    float4 r[8];
#pragma unroll
    for (int s = 0; s < 8; ++s)
        r[s] = *reinterpret_cast<const float4*>(gbase + (size_t)s * 8 * RD);

    for (int c = 0; c < NCH; ++c) {
        __syncthreads();                  // LDS consumers of chunk c-1 done
#pragma unroll
        for (int s = 0; s < 8; ++s)
            *reinterpret_cast<float4*>(&smem[lbase + s * 8 * LROW]) = r[s];
        __syncthreads();                  // chunk c staged

        if (c + 1 < NCH) {
            const float* gnext = gbase + (c + 1) * CH;
#pragma unroll
            for (int s = 0; s < 8; ++s)
                r[s] = *reinterpret_cast<const float4*>(gnext + (size_t)s * 8 * RD);
        }

        // my token's K-quarter slice of this chunk -> registers
        float xv[SEG];
#pragma unroll
        for (int j = 0; j < SEG / 4; ++j) {
            const float4 q = *reinterpret_cast<const float4*>(
                &smem[token * LROW + kq * SEG + j * 4]);
            xv[j * 4 + 0] = q.x; xv[j * 4 + 1] = q.y;
            xv[j * 4 + 2] = q.z; xv[j * 4 + 3] = q.w;
        }

        // W: wave-uniform offset -> scalar loads (off the vector-mem path)
        const int woff = __builtin_amdgcn_readfirstlane(c * CH + kq * SEG);
#pragma unroll
        for (int e = 0; e < RE; ++e) {
            const float* wgp = Wg + e * RD + woff;
            const float* wnp = Wn + e * RD + woff;
#pragma unroll
            for (int j = 0; j < SEG; ++j) {
                accg[e] = fmaf(xv[j], wgp[j], accg[e]);
                accn[e] = fmaf(xv[j], wnp[j], accn[e]);
            }
        }
    }

    // ---- cross-kq reduction via LDS overlay ----
    __syncthreads();                      // last chunk's reads done
    {
        const int roff = (kq * TOKB + token) * REDW;
        *reinterpret_cast<float4*>(&smem[roff + 0])  = make_float4(accg[0], accg[1], accg[2], accg[3]);
        *reinterpret_cast<float4*>(&smem[roff + 4])  = make_float4(accg[4], accg[5], accg[6], accg[7]);
        *reinterpret_cast<float4*>(&smem[roff + 8])  = make_float4(accn[0], accn[1], accn[2], accn[3]);
        *reinterpret_cast<float4*>(&smem[roff + 12]) = make_float4(accn[4], accn[5], accn[6], accn[7]);
    }
    __syncthreads();

    if (tid < TOKB) {
        const int l = tid;
        const int tok = tokBase + l;

        float g[RE], nn[RE];
#pragma unroll
        for (int e = 0; e < RE; ++e) { g[e] = 0.f; nn[e] = 0.f; }
#pragma unroll
        for (int q = 0; q < KQ; ++q) {
            const int roff = (q * TOKB + l) * REDW;
            const float4 a0 = *reinterpret_cast<const float4*>(&smem[roff + 0]);
            const float4 a1 = *reinterpret_cast<const float4*>(&smem[roff + 4]);
            const float4 b0 = *reinterpret_cast<const float4*>(&smem[roff + 8]);
            const float4 b1 = *reinterpret_cast<const float4*>(&smem[roff + 12]);
            g[0] += a0.x; g[1] += a0.y; g[2] += a0.z; g[3] += a0.w;
            g[4] += a1.x; g[5] += a1.y; g[6] += a1.z; g[7] += a1.w;
            nn[0] += b0.x; nn[1] += b0.y; nn[2] += b0.z; nn[3] += b0.w;
            nn[4] += b1.x; nn[5] += b1.y; nn[6] += b1.z; nn[7] += b1.w;
        }

        const float4* nzp = reinterpret_cast<const float4*>(noise + (size_t)tok * RE);
        const float4 nz0 = nzp[0];
        const float4 nz1 = nzp[1];
        const float nzv[RE] = {nz0.x, nz0.y, nz0.z, nz0.w,
                               nz1.x, nz1.y, nz1.z, nz1.w};

        float v[RE];
#pragma unroll
        for (int e = 0; e < RE; ++e) {
            const float p = nn[e] + bn[e];
            // stable softplus: max(p,0) + log1p(exp(-|p|))
            const float sp = fmaxf(p, 0.f) + log1pf(expf(-fabsf(p)));
            v[e] = fmaf(nzv[e], sp, g[e] + bg[e]);
        }

        // top-2 of 8; strict '>' keeps the lowest index on ties, matching
        // jax.lax.top_k / torch.topk ordering.
        int i1 = 0; float m1 = v[0];
#pragma unroll
        for (int e = 1; e < RE; ++e)
            if (v[e] > m1) { m1 = v[e]; i1 = e; }
        int i2 = -1; float m2 = -INFINITY;
#pragma unroll
        for (int e = 0; e < RE; ++e)
            if (e != i1 && v[e] > m2) { m2 = v[e]; i2 = e; }

        const float e2 = expf(m2 - m1);
        const float inv = 1.f / (1.f + e2);
        const float p1 = inv;
        const float p2 = e2 * inv;

        float rr[RE];
#pragma unroll
        for (int e = 0; e < RE; ++e)
            rr[e] = (e == i1) ? p1 : ((e == i2) ? p2 : 0.f);

        float4* orow = reinterpret_cast<float4*>(out_router + (size_t)tok * RE);
        orow[0] = make_float4(rr[0], rr[1], rr[2], rr[3]);
        orow[1] = make_float4(rr[4], rr[5], rr[6], rr[7]);

        float2* erow = reinterpret_cast<float2*>(out_experts + (size_t)tok * 2);
        *erow = make_float2((float)i1, (float)i2);
    }
}

extern "C" void kernel_launch(void* const* d_in, const int* in_sizes, int n_in,
                              void* d_out, int out_size, void* d_ws, size_t ws_size,
                              hipStream_t stream) {
    const float* x   = (const float*)d_in[0];
    const float* Wg  = (const float*)d_in[1];
    const float* bg  = (const float*)d_in[2];
    const float* Wn  = (const float*)d_in[3];
    const float* bn  = (const float*)d_in[4];
    const float* nz  = (const float*)d_in[5];
    const int T = in_sizes[0] / RD;              // 32768

    float* out_router  = (float*)d_out;                // T*8 floats
    float* out_experts = out_router + (size_t)T * RE;  // T*2 floats (as f32)

    const int blocks = T / TOKB;                 // 512
    hipLaunchKernelGGL(noisy_topk_router_kernel, dim3(blocks), dim3(256), 0,
                       stream, x, Wg, bg, Wn, bn, nz, out_router, out_experts);
}

// Round 5
// 132.298 us; speedup vs baseline: 1.2046x; 1.2046x over previous
//
#include <hip/hip_runtime.h>
#include <math.h>

// NoisyTopkRouter: x[T,2048] @ {Wg,Wn}[8,2048]^T -> logits[T,8] each,
// noisy = noise * softplus(noisy_pre) + gate; top-2 -> softmax -> scatter.
// T = 32768, D = 2048, E = 8, k = 2.
//
// R5: spill fix. R3/R4 spilled because bare __launch_bounds__(256) budgets
// only 64 VGPRs (compiler targets 8 waves/SIMD); scratch RMW traffic (189-273
// MB WRITE_SIZE) poisoned both. Now: __launch_bounds__(256,4) -> 128-VGPR
// budget, and live set cut to ~65: wave-pair structure (wave role = gate OR
// noise -> 8 outputs), 4 tokens/pair -> acc[4][8]=32 regs. All global loads
// stay wave-contiguous 1 KB. Butterfly shfl_xor finish, 512 B LDS exchange.

#define RD 2048
#define RE 8            // outputs per wave (its matrix's 8 experts)
#define TPP 4           // tokens per wave-pair
#define CHUNK 256       // d's per chunk (64 lanes x float4)
#define NCHUNK (RD / CHUNK)

__global__ __launch_bounds__(256, 4) void noisy_topk_router_kernel(
    const float* __restrict__ x,
    const float* __restrict__ Wg,
    const float* __restrict__ bg,
    const float* __restrict__ Wn,
    const float* __restrict__ bn,
    const float* __restrict__ noise,
    float* __restrict__ out_router,
    float* __restrict__ out_experts)
{
    __shared__ float red[2][2][TPP][RE];   // [pair][role][token][e], 512 B

    const int tid  = threadIdx.x;
    const int wid  = tid >> 6;             // wave 0..3
    const int l    = tid & 63;             // lane
    const int pair = wid >> 1;             // 0..1
    const int role = wid & 1;              // 0 = gate, 1 = noise
    const int tokBase = blockIdx.x * (2 * TPP) + pair * TPP;

    const float* __restrict__ W = role ? Wn : Wg;

    float acc[TPP][RE];
#pragma unroll
    for (int t = 0; t < TPP; ++t)
#pragma unroll
        for (int e = 0; e < RE; ++e) acc[t][e] = 0.f;

    const int lq = l * 4;                  // lane's float4 offset in chunk

#pragma unroll 1
    for (int c = 0; c < NCHUNK; ++c) {
        const int dbase = c * CHUNK + lq;
        // 4 coalesced 1 KB x loads (pair-partner wave re-reads -> L1 hit)
        float4 xv[TPP];
#pragma unroll
        for (int t = 0; t < TPP; ++t)
            xv[t] = *reinterpret_cast<const float4*>(
                x + (size_t)(tokBase + t) * RD + dbase);

#pragma unroll
        for (int e = 0; e < RE; ++e) {
            const float4 wv = *reinterpret_cast<const float4*>(W + e * RD + dbase);
#pragma unroll
            for (int t = 0; t < TPP; ++t) {
                acc[t][e] = fmaf(xv[t].x, wv.x, acc[t][e]);
                acc[t][e] = fmaf(xv[t].y, wv.y, acc[t][e]);
                acc[t][e] = fmaf(xv[t].z, wv.z, acc[t][e]);
                acc[t][e] = fmaf(xv[t].w, wv.w, acc[t][e]);
            }
        }
    }

    // 6-stage butterfly: every lane ends with the full 32 dot products
    // (fixed order -> deterministic).
#pragma unroll
    for (int m = 1; m < 64; m <<= 1)
#pragma unroll
        for (int t = 0; t < TPP; ++t)
#pragma unroll
            for (int e = 0; e < RE; ++e)
                acc[t][e] += __shfl_xor(acc[t][e], m, 64);

    // lanes 0..31 of each wave publish (token, e) to LDS
    if (l < 32) {
        const int t = l >> 3;
        const int e = l & 7;
        float v = acc[0][e];
        v = (t == 1) ? acc[1][e] : v;
        v = (t == 2) ? acc[2][e] : v;
        v = (t == 3) ? acc[3][e] : v;
        red[pair][role][t][e] = v;
    }
    __syncthreads();

    // 8 epilogue threads, one token each
    if (tid < 2 * TPP) {
        const int p = tid >> 2;
        const int t = tid & 3;
        const int tok = blockIdx.x * (2 * TPP) + tid;   // = p*4 + t offset

        const float4* nzp = reinterpret_cast<const float4*>(noise + (size_t)tok * RE);
        const float4 nz0 = nzp[0];
        const float4 nz1 = nzp[1];
        const float nzv[RE] = {nz0.x, nz0.y, nz0.z, nz0.w,
                               nz1.x, nz1.y, nz1.z, nz1.w};

        float v[RE];
#pragma unroll
        for (int e = 0; e < RE; ++e) {
            const float pn = red[p][1][t][e] + bn[e];
            // stable softplus: max(p,0) + log1p(exp(-|p|))
            const float sp = fmaxf(pn, 0.f) + log1pf(expf(-fabsf(pn)));
            v[e] = fmaf(nzv[e], sp, red[p][0][t][e] + bg[e]);
        }

        // top-2 of 8; strict '>' keeps the lowest index on ties, matching
        // jax.lax.top_k / torch.topk ordering.
        int i1 = 0; float m1 = v[0];
#pragma unroll
        for (int e = 1; e < RE; ++e)
            if (v[e] > m1) { m1 = v[e]; i1 = e; }
        int i2 = -1; float m2 = -INFINITY;
#pragma unroll
        for (int e = 0; e < RE; ++e)
            if (e != i1 && v[e] > m2) { m2 = v[e]; i2 = e; }

        const float e2 = expf(m2 - m1);
        const float inv = 1.f / (1.f + e2);
        const float p1 = inv;
        const float p2 = e2 * inv;

        float r[RE];
#pragma unroll
        for (int e = 0; e < RE; ++e)
            r[e] = (e == i1) ? p1 : ((e == i2) ? p2 : 0.f);

        float4* orow = reinterpret_cast<float4*>(out_router + (size_t)tok * RE);
        orow[0] = make_float4(r[0], r[1], r[2], r[3]);
        orow[1] = make_float4(r[4], r[5], r[6], r[7]);

        float2* erow = reinterpret_cast<float2*>(out_experts + (size_t)tok * 2);
        *erow = make_float2((float)i1, (float)i2);
    }
}

extern "C" void kernel_launch(void* const* d_in, const int* in_sizes, int n_in,
                              void* d_out, int out_size, void* d_ws, size_t ws_size,
                              hipStream_t stream) {
    const float* x   = (const float*)d_in[0];
    const float* Wg  = (const float*)d_in[1];
    const float* bg  = (const float*)d_in[2];
    const float* Wn  = (const float*)d_in[3];
    const float* bn  = (const float*)d_in[4];
    const float* nz  = (const float*)d_in[5];
    const int T = in_sizes[0] / RD;              // 32768

    float* out_router  = (float*)d_out;                // T*8 floats
    float* out_experts = out_router + (size_t)T * RE;  // T*2 floats (as f32)

    const int blocks = T / (2 * TPP);            // 4096 (8 tokens per block)
    hipLaunchKernelGGL(noisy_topk_router_kernel, dim3(blocks), dim3(256), 0,
                       stream, x, Wg, bg, Wn, bn, nz, out_router, out_experts);
}

// Round 6
// 82.903 us; speedup vs baseline: 1.9224x; 1.5958x over previous
//
#include <hip/hip_runtime.h>
#include <math.h>

// NoisyTopkRouter: x[T,2048] @ {Wg,Wn}[8,2048]^T -> logits[T,8] each,
// noisy = noise * softplus(noisy_pre) + gate; top-2 -> softmax -> scatter.
// T = 32768, D = 2048, E = 8, k = 2.
//
// R6: spill-proof + async-DMA structure.
//  - x staged HBM->LDS with global_load_lds (no staging VGPRs), 2-phase
//    double buffer; XOR-swizzled via pre-swizzled global source (LDS dest
//    must stay linear), swizzled ds_read_b128 on the consume side.
//  - W pre-transposed to WT[d][16] (kernel 1, into d_ws) and read as
//    wave-uniform scalars -> s_load path, zero vector-mem traffic.
//  - lane = token, wave owns a 32-d sub-range per 128-d chunk, acc[16].
//    Live VGPRs ~40 -> immune to the allocator caps that spilled R3/R4/R5.

#define RD 2048
#define RE 8
#define NE16 16               // stacked experts: 0..7 = gate, 8..15 = noise
#define TOKB 64               // tokens per block (lane = token)
#define CH 128                // d's per chunk
#define NCH (RD / CH)         // 16
#define NW 4                  // waves per block
#define REDW 20               // padded reduction row (floats)

#define AS1 __attribute__((address_space(1)))
#define AS3 __attribute__((address_space(3)))

__device__ __forceinline__ void gload_lds16(const float* g, float* l) {
    // HBM -> LDS DMA, 16 B per lane; LDS dest is wave-uniform base + lane*16.
    __builtin_amdgcn_global_load_lds((const AS1 unsigned int*)g,
                                     (AS3 unsigned int*)l, 16, 0, 0);
}

// ---- kernel 1: WT[d][e] = (e<8 ? Wg[e][d] : Wn[e-8][d]),  d_ws scratch ----
__global__ __launch_bounds__(256) void transpose_w_kernel(
    const float* __restrict__ Wg, const float* __restrict__ Wn,
    float* __restrict__ WT)
{
    const int idx = blockIdx.x * 256 + threadIdx.x;   // 0 .. 2048*16-1
    const int d = idx >> 4;
    const int e = idx & 15;
    const float v = (e < 8) ? Wg[e * RD + d] : Wn[(e - 8) * RD + d];
    WT[idx] = v;                                      // coalesced write
}

// ---- kernel 2: the router ----
__global__ __launch_bounds__(256) void noisy_topk_router_kernel(
    const float* __restrict__ x,
    const float* __restrict__ WT,     // [2048][16] transposed weights
    const float* __restrict__ bg,
    const float* __restrict__ bn,
    const float* __restrict__ noise,
    float* __restrict__ out_router,
    float* __restrict__ out_experts)
{
    __shared__ float xb[2][TOKB * CH];   // 2 x 32 KB double buffer

    const int tid = threadIdx.x;
    const int w = tid >> 6;              // wave 0..3 -> d-sub-range of chunk
    const int l = tid & 63;              // lane = token within tile
    const int tokBase = blockIdx.x * TOKB;

    // staging geometry: wave w issues insts s=0..7; inst (w,s) fills LDS
    // floats [(w*8+s)*256, +256) = token rows t0=(w*8+s)*2 and t0+1.
    // lane i -> row t = t0+(i>>5), phys seg p = i&31; source is the
    // XOR-pre-swizzled global seg (p ^ (t&7)) so reads can de-swizzle.
    const int t_mine = ((w * 8) * 2) /*recomputed per s below*/;
    (void)t_mine;

    float acc[NE16];
#pragma unroll
    for (int e = 0; e < NE16; ++e) acc[e] = 0.f;

    // prologue: stage chunk 0 into buf 0
    {
        const int c = 0;
#pragma unroll
        for (int s = 0; s < 8; ++s) {
            const int t = (w * 8 + s) * 2 + (l >> 5);
            const int p = l & 31;
            const float* gsrc = x + (size_t)(tokBase + t) * RD + c * CH
                                + ((p ^ (t & 7)) << 2);
            gload_lds16(gsrc, &xb[0][(w * 8 + s) * 256]);
        }
    }
    __syncthreads();   // drains vmcnt -> chunk 0 resident

#pragma unroll 1
    for (int c = 0; c < NCH; ++c) {
        const int buf = c & 1;

        // phase A: issue next chunk's DMA into the other buffer
        if (c + 1 < NCH) {
#pragma unroll
            for (int s = 0; s < 8; ++s) {
                const int t = (w * 8 + s) * 2 + (l >> 5);
                const int p = l & 31;
                const float* gsrc = x + (size_t)(tokBase + t) * RD
                                    + (c + 1) * CH + ((p ^ (t & 7)) << 2);
                gload_lds16(gsrc, &xb[buf ^ 1][(w * 8 + s) * 256]);
            }
        }

        // phase B: consume current chunk. wave w covers logical segs
        // q = w*8 .. w*8+7 (d = c*128 + q*4 + dd). W row is wave-uniform.
        const int wbase = __builtin_amdgcn_readfirstlane((c * CH + w * 32) * NE16);
        const float* __restrict__ wt = WT + wbase;
#pragma unroll
        for (int jj = 0; jj < 8; ++jj) {
            const int q = w * 8 + jj;
            const float4 xq = *reinterpret_cast<const float4*>(
                &xb[buf][l * CH + ((q ^ (l & 7)) << 2)]);
            const float xs[4] = {xq.x, xq.y, xq.z, xq.w};
#pragma unroll
            for (int dd = 0; dd < 4; ++dd) {
                const float* wrow = wt + (jj * 4 + dd) * NE16;
#pragma unroll
                for (int e = 0; e < NE16; ++e)
                    acc[e] = fmaf(xs[dd], wrow[e], acc[e]);
            }
        }

        __syncthreads();   // waits vmcnt(0): next chunk landed; readers done
    }

    // ---- cross-wave reduction: overlay on xb[0] ----
    float* red = &xb[0][0];               // [NW][TOKB][REDW] = 20 KB < 32 KB
    {
        const int roff = (w * TOKB + l) * REDW;
        *reinterpret_cast<float4*>(&red[roff + 0])  = make_float4(acc[0], acc[1], acc[2], acc[3]);
        *reinterpret_cast<float4*>(&red[roff + 4])  = make_float4(acc[4], acc[5], acc[6], acc[7]);
        *reinterpret_cast<float4*>(&red[roff + 8])  = make_float4(acc[8], acc[9], acc[10], acc[11]);
        *reinterpret_cast<float4*>(&red[roff + 12]) = make_float4(acc[12], acc[13], acc[14], acc[15]);
    }
    __syncthreads();

    if (tid < TOKB) {
        const int tok = tokBase + l;

        float g[RE], nn[RE];
#pragma unroll
        for (int e = 0; e < RE; ++e) { g[e] = 0.f; nn[e] = 0.f; }
#pragma unroll
        for (int q = 0; q < NW; ++q) {
            const int roff = (q * TOKB + l) * REDW;
            const float4 a0 = *reinterpret_cast<const float4*>(&red[roff + 0]);
            const float4 a1 = *reinterpret_cast<const float4*>(&red[roff + 4]);
            const float4 b0 = *reinterpret_cast<const float4*>(&red[roff + 8]);
            const float4 b1 = *reinterpret_cast<const float4*>(&red[roff + 12]);
            g[0] += a0.x; g[1] += a0.y; g[2] += a0.z; g[3] += a0.w;
            g[4] += a1.x; g[5] += a1.y; g[6] += a1.z; g[7] += a1.w;
            nn[0] += b0.x; nn[1] += b0.y; nn[2] += b0.z; nn[3] += b0.w;
            nn[4] += b1.x; nn[5] += b1.y; nn[6] += b1.z; nn[7] += b1.w;
        }

        const float4* nzp = reinterpret_cast<const float4*>(noise + (size_t)tok * RE);
        const float4 nz0 = nzp[0];
        const float4 nz1 = nzp[1];
        const float nzv[RE] = {nz0.x, nz0.y, nz0.z, nz0.w,
                               nz1.x, nz1.y, nz1.z, nz1.w};

        float v[RE];
#pragma unroll
        for (int e = 0; e < RE; ++e) {
            const float p = nn[e] + bn[e];
            // stable softplus: max(p,0) + log1p(exp(-|p|))
            const float sp = fmaxf(p, 0.f) + log1pf(expf(-fabsf(p)));
            v[e] = fmaf(nzv[e], sp, g[e] + bg[e]);
        }

        // top-2 of 8; strict '>' keeps the lowest index on ties, matching
        // jax.lax.top_k / torch.topk ordering.
        int i1 = 0; float m1 = v[0];
#pragma unroll
        for (int e = 1; e < RE; ++e)
            if (v[e] > m1) { m1 = v[e]; i1 = e; }
        int i2 = -1; float m2 = -INFINITY;
#pragma unroll
        for (int e = 0; e < RE; ++e)
            if (e != i1 && v[e] > m2) { m2 = v[e]; i2 = e; }

        const float e2 = expf(m2 - m1);
        const float inv = 1.f / (1.f + e2);
        const float p1 = inv;
        const float p2 = e2 * inv;

        float r[RE];
#pragma unroll
        for (int e = 0; e < RE; ++e)
            r[e] = (e == i1) ? p1 : ((e == i2) ? p2 : 0.f);

        float4* orow = reinterpret_cast<float4*>(out_router + (size_t)tok * RE);
        orow[0] = make_float4(r[0], r[1], r[2], r[3]);
        orow[1] = make_float4(r[4], r[5], r[6], r[7]);

        float2* erow = reinterpret_cast<float2*>(out_experts + (size_t)tok * 2);
        *erow = make_float2((float)i1, (float)i2);
    }
}

extern "C" void kernel_launch(void* const* d_in, const int* in_sizes, int n_in,
                              void* d_out, int out_size, void* d_ws, size_t ws_size,
                              hipStream_t stream) {
    const float* x   = (const float*)d_in[0];
    const float* Wg  = (const float*)d_in[1];
    const float* bg  = (const float*)d_in[2];
    const float* Wn  = (const float*)d_in[3];
    const float* bn  = (const float*)d_in[4];
    const float* nz  = (const float*)d_in[5];
    const int T = in_sizes[0] / RD;              // 32768

    float* WT = (float*)d_ws;                    // 2048*16*4 = 128 KB scratch

    float* out_router  = (float*)d_out;                // T*8 floats
    float* out_experts = out_router + (size_t)T * RE;  // T*2 floats (as f32)

    hipLaunchKernelGGL(transpose_w_kernel, dim3((RD * NE16) / 256), dim3(256),
                       0, stream, Wg, Wn, WT);

    const int blocks = T / TOKB;                 // 512
    hipLaunchKernelGGL(noisy_topk_router_kernel, dim3(blocks), dim3(256), 0,
                       stream, x, WT, bg, bn, nz, out_router, out_experts);
}

// Round 7
// 62.234 us; speedup vs baseline: 2.5609x; 1.3321x over previous
//
#include <hip/hip_runtime.h>
#include <math.h>

// NoisyTopkRouter: x[T,2048] @ {Wg,Wn}[8,2048]^T -> logits[T,8] each,
// noisy = noise * softplus(noisy_pre) + gate; top-2 -> softmax -> scatter.
// T = 32768, D = 2048, E = 8, k = 2.
//
// R7: R6 structure (global_load_lds staging, XOR-pre-swizzled source,
// wave-uniform scalar W, acc[16]/lane) but with 2x the independent
// pipelines per CU: CH=64 (16 KB chunks, 32 KB LDS/block) and K split
// across 2 blocks -> 1024 blocks = 4 blocks/CU, 16 waves/CU. Partial
// logit sums land in d_ws; a small finalize kernel combines + epilogue.

#define RD 2048
#define RE 8
#define NE16 16               // stacked experts: 0..7 = gate, 8..15 = noise
#define TOKB 64               // tokens per block (lane = token)
#define CH 64                 // d's per chunk
#define KSL 2                 // K-slices (blocks per token tile)
#define KLEN (RD / KSL)       // 1024 d's per block
#define NCH (KLEN / CH)       // 16 chunks
#define NW 4                  // waves per block
#define REDW 20               // padded reduction row (floats)

#define AS1 __attribute__((address_space(1)))
#define AS3 __attribute__((address_space(3)))

__device__ __forceinline__ void gload_lds16(const float* g, float* l) {
    // HBM -> LDS DMA, 16 B per lane; LDS dest is wave-uniform base + lane*16.
    __builtin_amdgcn_global_load_lds((const AS1 unsigned int*)g,
                                     (AS3 unsigned int*)l, 16, 0, 0);
}

// ---- kernel 1: WT[d][e] = (e<8 ? Wg[e][d] : Wn[e-8][d]) ----
__global__ __launch_bounds__(256) void transpose_w_kernel(
    const float* __restrict__ Wg, const float* __restrict__ Wn,
    float* __restrict__ WT)
{
    const int idx = blockIdx.x * 256 + threadIdx.x;   // 0 .. 2048*16-1
    const int d = idx >> 4;
    const int e = idx & 15;
    WT[idx] = (e < 8) ? Wg[e * RD + d] : Wn[(e - 8) * RD + d];
}

// ---- kernel 2: main GEMV, one K-slice per block, partials to d_ws ----
__global__ __launch_bounds__(256) void router_main_kernel(
    const float* __restrict__ x,
    const float* __restrict__ WT,     // [2048][16]
    float* __restrict__ pws,          // [KSL][T][16] partial sums
    int T)
{
    __shared__ float xb[2][TOKB * CH];   // 2 x 16 KB double buffer

    const int tid = threadIdx.x;
    const int w = tid >> 6;              // wave 0..3 -> 16-d sub-range
    const int l = tid & 63;              // lane = token within tile
    const int kslice = blockIdx.x & 1;
    const int bt = blockIdx.x >> 1;
    const int tokBase = bt * TOKB;
    const int kbase = kslice * KLEN;

    float acc[NE16];
#pragma unroll
    for (int e = 0; e < NE16; ++e) acc[e] = 0.f;

    // staging: per chunk, wave w issues s=0..3; inst (w,s) fills rows
    // t0=(w*4+s)*4 .. +3 (64-float rows). lane -> row t=t0+(l>>4),
    // phys 16B-seg p=l&15; source seg is XOR-pre-swizzled (p ^ (t&7)).
    {
#pragma unroll
        for (int s = 0; s < 4; ++s) {
            const int t = (w * 4 + s) * 4 + (l >> 4);
            const int p = l & 15;
            const float* gsrc = x + (size_t)(tokBase + t) * RD + kbase
                                + ((p ^ (t & 7)) << 2);
            gload_lds16(gsrc, &xb[0][(w * 4 + s) * 256]);
        }
    }
    __syncthreads();   // drains vmcnt -> chunk 0 resident

#pragma unroll 1
    for (int c = 0; c < NCH; ++c) {
        const int buf = c & 1;

        if (c + 1 < NCH) {
#pragma unroll
            for (int s = 0; s < 4; ++s) {
                const int t = (w * 4 + s) * 4 + (l >> 4);
                const int p = l & 15;
                const float* gsrc = x + (size_t)(tokBase + t) * RD + kbase
                                    + (c + 1) * CH + ((p ^ (t & 7)) << 2);
                gload_lds16(gsrc, &xb[buf ^ 1][(w * 4 + s) * 256]);
            }
        }

        // consume: wave w covers logical segs s=w*4..w*4+3 (d = c*64+s*4+ii).
        // W base is wave-uniform -> scalar loads.
        const int wbase = __builtin_amdgcn_readfirstlane(
            (kbase + c * CH + w * 16) * NE16);
        const float* __restrict__ wt = WT + wbase;
#pragma unroll
        for (int r = 0; r < 4; ++r) {
            const int phys = (w * 4 + r) ^ (l & 7);
            const float4 xq = *reinterpret_cast<const float4*>(
                &xb[buf][l * CH + (phys << 2)]);
            const float xs[4] = {xq.x, xq.y, xq.z, xq.w};
#pragma unroll
            for (int ii = 0; ii < 4; ++ii) {
                const float* wrow = wt + (r * 4 + ii) * NE16;
#pragma unroll
                for (int e = 0; e < NE16; ++e)
                    acc[e] = fmaf(xs[ii], wrow[e], acc[e]);
            }
        }

        __syncthreads();   // next chunk landed; this chunk's readers done
    }

    // ---- cross-wave reduction via LDS overlay (xb flat = 8192 floats) ----
    float* red = &xb[0][0];
    {
        const int roff = (w * TOKB + l) * REDW;    // max 5112+4 < 8192
        *reinterpret_cast<float4*>(&red[roff + 0])  = make_float4(acc[0], acc[1], acc[2], acc[3]);
        *reinterpret_cast<float4*>(&red[roff + 4])  = make_float4(acc[4], acc[5], acc[6], acc[7]);
        *reinterpret_cast<float4*>(&red[roff + 8])  = make_float4(acc[8], acc[9], acc[10], acc[11]);
        *reinterpret_cast<float4*>(&red[roff + 12]) = make_float4(acc[12], acc[13], acc[14], acc[15]);
    }
    __syncthreads();

    // 256 threads: (token, quad) -> sum 4 wave partials, store one float4
    {
        const int tok = tid >> 2;
        const int q = tid & 3;
        float4 s = make_float4(0.f, 0.f, 0.f, 0.f);
#pragma unroll
        for (int wv = 0; wv < NW; ++wv) {
            const float4 a = *reinterpret_cast<const float4*>(
                &red[(wv * TOKB + tok) * REDW + q * 4]);
            s.x += a.x; s.y += a.y; s.z += a.z; s.w += a.w;
        }
        float* dst = pws + ((size_t)kslice * T + tokBase + tok) * NE16 + q * 4;
        *reinterpret_cast<float4*>(dst) = s;
    }
}

// ---- kernel 3: combine K-slices + epilogue ----
__global__ __launch_bounds__(256) void router_finalize_kernel(
    const float* __restrict__ pws,
    const float* __restrict__ bg,
    const float* __restrict__ bn,
    const float* __restrict__ noise,
    float* __restrict__ out_router,
    float* __restrict__ out_experts,
    int T)
{
    const int tok = blockIdx.x * 256 + threadIdx.x;

    const float* p0 = pws + (size_t)tok * NE16;
    const float* p1 = pws + ((size_t)T + tok) * NE16;

    float g[RE], nn[RE];
#pragma unroll
    for (int e = 0; e < RE; ++e) {
        g[e]  = p0[e] + p1[e] + bg[e];
        nn[e] = p0[8 + e] + p1[8 + e] + bn[e];
    }

    const float4* nzp = reinterpret_cast<const float4*>(noise + (size_t)tok * RE);
    const float4 nz0 = nzp[0];
    const float4 nz1 = nzp[1];
    const float nzv[RE] = {nz0.x, nz0.y, nz0.z, nz0.w,
                           nz1.x, nz1.y, nz1.z, nz1.w};

    float v[RE];
#pragma unroll
    for (int e = 0; e < RE; ++e) {
        const float p = nn[e];
        // stable softplus: max(p,0) + log1p(exp(-|p|))
        const float sp = fmaxf(p, 0.f) + log1pf(expf(-fabsf(p)));
        v[e] = fmaf(nzv[e], sp, g[e]);
    }

    // top-2 of 8; strict '>' keeps the lowest index on ties, matching
    // jax.lax.top_k / torch.topk ordering.
    int i1 = 0; float m1 = v[0];
#pragma unroll
    for (int e = 1; e < RE; ++e)
        if (v[e] > m1) { m1 = v[e]; i1 = e; }
    int i2 = -1; float m2 = -INFINITY;
#pragma unroll
    for (int e = 0; e < RE; ++e)
        if (e != i1 && v[e] > m2) { m2 = v[e]; i2 = e; }

    const float e2 = expf(m2 - m1);
    const float inv = 1.f / (1.f + e2);
    const float p1s = inv;
    const float p2s = e2 * inv;

    float r[RE];
#pragma unroll
    for (int e = 0; e < RE; ++e)
        r[e] = (e == i1) ? p1s : ((e == i2) ? p2s : 0.f);

    float4* orow = reinterpret_cast<float4*>(out_router + (size_t)tok * RE);
    orow[0] = make_float4(r[0], r[1], r[2], r[3]);
    orow[1] = make_float4(r[4], r[5], r[6], r[7]);

    float2* erow = reinterpret_cast<float2*>(out_experts + (size_t)tok * 2);
    *erow = make_float2((float)i1, (float)i2);
}

extern "C" void kernel_launch(void* const* d_in, const int* in_sizes, int n_in,
                              void* d_out, int out_size, void* d_ws, size_t ws_size,
                              hipStream_t stream) {
    const float* x   = (const float*)d_in[0];
    const float* Wg  = (const float*)d_in[1];
    const float* bg  = (const float*)d_in[2];
    const float* Wn  = (const float*)d_in[3];
    const float* bn  = (const float*)d_in[4];
    const float* nz  = (const float*)d_in[5];
    const int T = in_sizes[0] / RD;              // 32768

    float* WT  = (float*)d_ws;                   // 128 KB
    float* pws = WT + (size_t)RD * NE16;         // KSL*T*16 floats = 4 MB

    float* out_router  = (float*)d_out;                // T*8 floats
    float* out_experts = out_router + (size_t)T * RE;  // T*2 floats (as f32)

    hipLaunchKernelGGL(transpose_w_kernel, dim3((RD * NE16) / 256), dim3(256),
                       0, stream, Wg, Wn, WT);

    const int blocks = (T / TOKB) * KSL;         // 1024
    hipLaunchKernelGGL(router_main_kernel, dim3(blocks), dim3(256), 0,
                       stream, x, WT, pws, T);

    hipLaunchKernelGGL(router_finalize_kernel, dim3(T / 256), dim3(256), 0,
                       stream, pws, bg, bn, nz, out_router, out_experts, T);
}